// Round 4
// baseline (1814.464 us; speedup 1.0000x reference)
//
#include <hip/hip_runtime.h>
#include <stdint.h>

// Problem: B=2, S=2048, D=1024, H=16, dh=64
// Inputs fp32, OUTPUT fp32 (bf16-floored threshold permits bf16 internals).
#define SEQ    2048
#define DMODEL 1024

typedef __bf16 bf16x8 __attribute__((ext_vector_type(8)));
typedef float  f32x4  __attribute__((ext_vector_type(4)));

// ---------------------------------------------------------------------------
// GEMM: C[M x N] = A[M x K] @ B[K x N] + bias[N]
//   A: fp32 (A_IS_F32=true) or bf16 (false). B, bias: fp32.
// mode 0: scatter bf16 into Q/K/V [B,H,S,dh] (N=3072)
// mode 1: plain row-major FP32 store to Cplain (N=1024)
// ---------------------------------------------------------------------------
template<bool A_IS_F32>
__global__ __launch_bounds__(256)
void gemm_kernel(const void* __restrict__ Av, const float* __restrict__ Bw,
                 const float* __restrict__ bias,
                 __bf16* __restrict__ Cq, __bf16* __restrict__ Ck,
                 __bf16* __restrict__ Cv, float* __restrict__ Cplain,
                 int K, int N, int mode)
{
    __shared__ __attribute__((aligned(16))) __bf16 As[128][40];
    __shared__ __attribute__((aligned(16))) __bf16 Bs[128][40];

    const int t    = threadIdx.x;
    const int wave = t >> 6;
    const int lane = t & 63;
    const int l15  = lane & 15;
    const int quad = lane >> 4;
    const int wm   = (wave >> 1) * 64;
    const int wn   = (wave & 1) * 64;
    const int m0   = blockIdx.y * 128;
    const int n0   = blockIdx.x * 128;

    f32x4 acc[4][4] = {};

    for (int k0 = 0; k0 < K; k0 += 32) {
        __syncthreads();
        if (A_IS_F32) {
            const float* A = (const float*)Av;
            int idx = t * 4;
#pragma unroll
            for (int it = 0; it < 4; ++it) {
                int row = idx >> 5;
                int kk  = idx & 31;
                float4 v = *(const float4*)(A + (size_t)(m0 + row) * K + k0 + kk);
                __bf16 tmp[4] = { (__bf16)v.x, (__bf16)v.y, (__bf16)v.z, (__bf16)v.w };
                *(uint2*)(&As[row][kk]) = *(uint2*)tmp;
                idx += 1024;
            }
        } else {
            const __bf16* A = (const __bf16*)Av;
            int idx = t * 8;
#pragma unroll
            for (int it = 0; it < 2; ++it) {
                int row = idx >> 5;
                int kk  = idx & 31;
                uint4 v = *(const uint4*)(A + (size_t)(m0 + row) * K + k0 + kk);
                *(uint4*)(&As[row][kk]) = v;
                idx += 2048;
            }
        }
        {
            int idx = t * 4;
#pragma unroll
            for (int it = 0; it < 4; ++it) {
                int kr = idx >> 7;
                int nn = idx & 127;
                float4 v = *(const float4*)(Bw + (size_t)(k0 + kr) * N + n0 + nn);
                Bs[nn + 0][kr] = (__bf16)v.x;
                Bs[nn + 1][kr] = (__bf16)v.y;
                Bs[nn + 2][kr] = (__bf16)v.z;
                Bs[nn + 3][kr] = (__bf16)v.w;
                idx += 1024;
            }
        }
        __syncthreads();

        bf16x8 af[4], bfr[4];
#pragma unroll
        for (int mi = 0; mi < 4; ++mi)
            af[mi] = *(const bf16x8*)(&As[wm + mi * 16 + l15][quad * 8]);
#pragma unroll
        for (int ni = 0; ni < 4; ++ni)
            bfr[ni] = *(const bf16x8*)(&Bs[wn + ni * 16 + l15][quad * 8]);
#pragma unroll
        for (int mi = 0; mi < 4; ++mi)
#pragma unroll
            for (int ni = 0; ni < 4; ++ni)
                acc[mi][ni] = __builtin_amdgcn_mfma_f32_16x16x32_bf16(
                    af[mi], bfr[ni], acc[mi][ni], 0, 0, 0);
    }

#pragma unroll
    for (int mi = 0; mi < 4; ++mi) {
        int rowb = m0 + wm + mi * 16 + quad * 4;
#pragma unroll
        for (int ni = 0; ni < 4; ++ni) {
            int col = n0 + wn + ni * 16 + l15;
            float bia = bias[col];
#pragma unroll
            for (int r = 0; r < 4; ++r) {
                float v = acc[mi][ni][r] + bia;
                int rr = rowb + r;
                if (mode == 0) {
                    int b = rr >> 11;
                    int s = rr & 2047;
                    int part = col >> 10;
                    int rem  = col & 1023;
                    int h = rem >> 6;
                    int d = rem & 63;
                    __bf16* dst = (part == 0) ? Cq : (part == 1) ? Ck : Cv;
                    dst[(((size_t)(b * 16 + h)) * SEQ + s) * 64 + d] = (__bf16)v;
                } else {
                    Cplain[(size_t)rr * N + col] = v;   // FP32 output
                }
            }
        }
    }
}

// ---------------------------------------------------------------------------
// Pure-VALU flash attention (kept identical to R3 for clean bisect).
// One thread per query row; K/V tiles in LDS; scalar online softmax.
// grid (B*H = 32, S/256 = 8), block 256.
// ---------------------------------------------------------------------------
__global__ __launch_bounds__(256)
void attn_valu(const __bf16* __restrict__ Q, const __bf16* __restrict__ Kb,
               const __bf16* __restrict__ Vb, const float* __restrict__ mask,
               __bf16* __restrict__ Out)
{
    __shared__ __attribute__((aligned(16))) __bf16 Ksh[64][64];
    __shared__ __attribute__((aligned(16))) __bf16 Vsh[64][64];

    const int t  = threadIdx.x;
    const int bh = blockIdx.x;
    const int b  = bh >> 4;
    const int h  = bh & 15;
    const int q  = blockIdx.y * 256 + t;

    const __bf16* Qp = Q  + (size_t)bh * SEQ * 64;
    const __bf16* Kp = Kb + (size_t)bh * SEQ * 64;
    const __bf16* Vp = Vb + (size_t)bh * SEQ * 64;
    const float*  Mp = mask + (size_t)b * SEQ * SEQ + (size_t)q * SEQ;

    float qr[64];
#pragma unroll
    for (int i = 0; i < 8; ++i) {
        bf16x8 v = *(const bf16x8*)(Qp + (size_t)q * 64 + i * 8);
#pragma unroll
        for (int j = 0; j < 8; ++j) qr[i * 8 + j] = (float)v[j];
    }

    float o[64];
#pragma unroll
    for (int d = 0; d < 64; ++d) o[d] = 0.f;
    float mrun = -1e30f, lrun = 0.f;

    for (int kt = 0; kt < SEQ / 64; ++kt) {
        const int key0 = kt * 64;
        __syncthreads();
        {
            int idx = t * 8;
#pragma unroll
            for (int half = 0; half < 2; ++half) {
                int kr = idx >> 6;
                int d  = idx & 63;
                *(uint4*)(&Ksh[kr][d]) = *(const uint4*)(Kp + (size_t)(key0 + kr) * 64 + d);
                *(uint4*)(&Vsh[kr][d]) = *(const uint4*)(Vp + (size_t)(key0 + kr) * 64 + d);
                idx += 2048;
            }
        }
        __syncthreads();

        for (int kg = 0; kg < 8; ++kg) {
            float s[8];
#pragma unroll
            for (int j = 0; j < 8; ++j) {
                const __bf16* kk = &Ksh[kg * 8 + j][0];
                float acc = 0.f;
#pragma unroll
                for (int i = 0; i < 8; ++i) {
                    bf16x8 kv = *(const bf16x8*)(kk + i * 8);
#pragma unroll
                    for (int jj = 0; jj < 8; ++jj)
                        acc += qr[i * 8 + jj] * (float)kv[jj];
                }
                s[j] = acc;
            }
            float mv[8];
            {
                float4 m0v = *(const float4*)(Mp + key0 + kg * 8);
                float4 m1v = *(const float4*)(Mp + key0 + kg * 8 + 4);
                mv[0] = m0v.x; mv[1] = m0v.y; mv[2] = m0v.z; mv[3] = m0v.w;
                mv[4] = m1v.x; mv[5] = m1v.y; mv[6] = m1v.z; mv[7] = m1v.w;
            }
#pragma unroll
            for (int j = 0; j < 8; ++j)
                s[j] = s[j] * 0.125f * mv[j] + (mv[j] - 1.0f) * 10000.0f;
            float mx = s[0];
#pragma unroll
            for (int j = 1; j < 8; ++j) mx = fmaxf(mx, s[j]);
            float mnew = fmaxf(mrun, mx);
            float a = __expf(mrun - mnew);
            mrun = mnew;
            float ps = 0.f;
#pragma unroll
            for (int j = 0; j < 8; ++j) { s[j] = __expf(s[j] - mnew); ps += s[j]; }
            lrun = lrun * a + ps;
#pragma unroll
            for (int d = 0; d < 64; ++d) o[d] *= a;
#pragma unroll
            for (int j = 0; j < 8; ++j) {
                const __bf16* vr = &Vsh[kg * 8 + j][0];
                float p = s[j];
#pragma unroll
                for (int i = 0; i < 8; ++i) {
                    bf16x8 vv = *(const bf16x8*)(vr + i * 8);
#pragma unroll
                    for (int jj = 0; jj < 8; ++jj)
                        o[i * 8 + jj] += p * (float)vv[jj];
                }
            }
        }
    }
    const float inv = 1.0f / lrun;
    __bf16* op = Out + ((size_t)(b * SEQ + q)) * DMODEL + h * 64;
#pragma unroll
    for (int d = 0; d < 64; ++d) op[d] = (__bf16)(o[d] * inv);
}

// ---------------------------------------------------------------------------
extern "C" void kernel_launch(void* const* d_in, const int* in_sizes, int n_in,
                              void* d_out, int out_size, void* d_ws, size_t ws_size,
                              hipStream_t stream)
{
    // Defensive size-keyed remap (all six sizes are distinct); identity if the
    // documented setup_inputs() dict order holds.
    const float* src  = nullptr;  // 2*2048*1024 = 4194304
    const float* mask = nullptr;  // 2*2048*2048 = 8388608
    const float* Wqkv = nullptr;  // 1024*3072   = 3145728
    const float* bqkv = nullptr;  // 3072
    const float* Wout = nullptr;  // 1024*1024   = 1048576
    const float* bout = nullptr;  // 1024
    for (int i = 0; i < n_in; ++i) {
        switch (in_sizes[i]) {
            case 4194304: src  = (const float*)d_in[i]; break;
            case 8388608: mask = (const float*)d_in[i]; break;
            case 3145728: Wqkv = (const float*)d_in[i]; break;
            case 3072:    bqkv = (const float*)d_in[i]; break;
            case 1048576: Wout = (const float*)d_in[i]; break;
            case 1024:    bout = (const float*)d_in[i]; break;
        }
    }
    float* out = (float*)d_out;                  // [2,2048,1024] FP32

    const size_t NE = (size_t)2 * 16 * SEQ * 64; // 4M elems per tensor
    __bf16* Qb = (__bf16*)d_ws;
    __bf16* Kb = Qb + NE;
    __bf16* Vb = Kb + NE;
    __bf16* Ao = Vb + NE;                        // attn out [B*S, 1024] bf16

    gemm_kernel<true><<<dim3(3072 / 128, 4096 / 128), 256, 0, stream>>>(
        (const void*)src, Wqkv, bqkv, Qb, Kb, Vb, nullptr, 1024, 3072, 0);

    attn_valu<<<dim3(32, SEQ / 256), 256, 0, stream>>>(Qb, Kb, Vb, mask, Ao);

    gemm_kernel<false><<<dim3(1024 / 128, 4096 / 128), 256, 0, stream>>>(
        (const void*)Ao, Wout, bout, nullptr, nullptr, nullptr, out, 1024, 1024, 1);
}

// Round 5
// 451.481 us; speedup vs baseline: 4.0189x; 4.0189x over previous
//
#include <hip/hip_runtime.h>
#include <stdint.h>

// Problem: B=2, S=2048, D=1024, H=16, dh=64
// Inputs fp32, OUTPUT fp32. Internals bf16 (threshold has bf16 floor).
#define SEQ    2048
#define DMODEL 1024

typedef __bf16 bf16x8 __attribute__((ext_vector_type(8)));
typedef float  f32x4  __attribute__((ext_vector_type(4)));

// ---------------------------------------------------------------------------
// GEMM: C[M x N] = A[M x K] @ B[K x N] + bias[N]   (unchanged from R4 PASS)
//   A: fp32 (A_IS_F32=true) or bf16 (false). B, bias: fp32.
// mode 0: scatter bf16 into Q/K/V [B,H,S,dh] (N=3072)
// mode 1: plain row-major FP32 store to Cplain (N=1024)
// ---------------------------------------------------------------------------
template<bool A_IS_F32>
__global__ __launch_bounds__(256)
void gemm_kernel(const void* __restrict__ Av, const float* __restrict__ Bw,
                 const float* __restrict__ bias,
                 __bf16* __restrict__ Cq, __bf16* __restrict__ Ck,
                 __bf16* __restrict__ Cv, float* __restrict__ Cplain,
                 int K, int N, int mode)
{
    __shared__ __attribute__((aligned(16))) __bf16 As[128][40];
    __shared__ __attribute__((aligned(16))) __bf16 Bs[128][40];

    const int t    = threadIdx.x;
    const int wave = t >> 6;
    const int lane = t & 63;
    const int l15  = lane & 15;
    const int quad = lane >> 4;
    const int wm   = (wave >> 1) * 64;
    const int wn   = (wave & 1) * 64;
    const int m0   = blockIdx.y * 128;
    const int n0   = blockIdx.x * 128;

    f32x4 acc[4][4] = {};

    for (int k0 = 0; k0 < K; k0 += 32) {
        __syncthreads();
        if (A_IS_F32) {
            const float* A = (const float*)Av;
            int idx = t * 4;
#pragma unroll
            for (int it = 0; it < 4; ++it) {
                int row = idx >> 5;
                int kk  = idx & 31;
                float4 v = *(const float4*)(A + (size_t)(m0 + row) * K + k0 + kk);
                __bf16 tmp[4] = { (__bf16)v.x, (__bf16)v.y, (__bf16)v.z, (__bf16)v.w };
                *(uint2*)(&As[row][kk]) = *(uint2*)tmp;
                idx += 1024;
            }
        } else {
            const __bf16* A = (const __bf16*)Av;
            int idx = t * 8;
#pragma unroll
            for (int it = 0; it < 2; ++it) {
                int row = idx >> 5;
                int kk  = idx & 31;
                uint4 v = *(const uint4*)(A + (size_t)(m0 + row) * K + k0 + kk);
                *(uint4*)(&As[row][kk]) = v;
                idx += 2048;
            }
        }
        {
            int idx = t * 4;
#pragma unroll
            for (int it = 0; it < 4; ++it) {
                int kr = idx >> 7;
                int nn = idx & 127;
                float4 v = *(const float4*)(Bw + (size_t)(k0 + kr) * N + n0 + nn);
                Bs[nn + 0][kr] = (__bf16)v.x;
                Bs[nn + 1][kr] = (__bf16)v.y;
                Bs[nn + 2][kr] = (__bf16)v.z;
                Bs[nn + 3][kr] = (__bf16)v.w;
                idx += 1024;
            }
        }
        __syncthreads();

        bf16x8 af[4], bfr[4];
#pragma unroll
        for (int mi = 0; mi < 4; ++mi)
            af[mi] = *(const bf16x8*)(&As[wm + mi * 16 + l15][quad * 8]);
#pragma unroll
        for (int ni = 0; ni < 4; ++ni)
            bfr[ni] = *(const bf16x8*)(&Bs[wn + ni * 16 + l15][quad * 8]);
#pragma unroll
        for (int mi = 0; mi < 4; ++mi)
#pragma unroll
            for (int ni = 0; ni < 4; ++ni)
                acc[mi][ni] = __builtin_amdgcn_mfma_f32_16x16x32_bf16(
                    af[mi], bfr[ni], acc[mi][ni], 0, 0, 0);
    }

#pragma unroll
    for (int mi = 0; mi < 4; ++mi) {
        int rowb = m0 + wm + mi * 16 + quad * 4;
#pragma unroll
        for (int ni = 0; ni < 4; ++ni) {
            int col = n0 + wn + ni * 16 + l15;
            float bia = bias[col];
#pragma unroll
            for (int r = 0; r < 4; ++r) {
                float v = acc[mi][ni][r] + bia;
                int rr = rowb + r;
                if (mode == 0) {
                    int b = rr >> 11;
                    int s = rr & 2047;
                    int part = col >> 10;
                    int rem  = col & 1023;
                    int h = rem >> 6;
                    int d = rem & 63;
                    __bf16* dst = (part == 0) ? Cq : (part == 1) ? Ck : Cv;
                    dst[(((size_t)(b * 16 + h)) * SEQ + s) * 64 + d] = (__bf16)v;
                } else {
                    Cplain[(size_t)rr * N + col] = v;   // FP32 output
                }
            }
        }
    }
}

// ---------------------------------------------------------------------------
// MFMA flash attention (R2 math, values validated by the R2==R3 absmax match).
// grid (B*H=32, S/64=32); 4 waves, each wave owns 16 q rows.
// scores = (QK^T)*0.125*mask + (mask-1)*1e4 ; online softmax ; O = P V
// Q/K/V bf16 [B,H,S,dh]; mask fp32 [B,S,S]; Out bf16 [B,S,D]
// ---------------------------------------------------------------------------
__global__ __launch_bounds__(256)
void attn_kernel(const __bf16* __restrict__ Q, const __bf16* __restrict__ Kb,
                 const __bf16* __restrict__ Vb, const float* __restrict__ mask,
                 __bf16* __restrict__ Out)
{
    __shared__ __attribute__((aligned(16))) __bf16 Vt[64][72];     // [d][key]
    __shared__ __attribute__((aligned(16))) __bf16 Ps[4][16][72];  // per-wave P [q][key]

    const int t    = threadIdx.x;
    const int wave = t >> 6;
    const int lane = t & 63;
    const int l15  = lane & 15;
    const int quad = lane >> 4;
    const int bh   = blockIdx.x;        // 0..31
    const int b    = bh >> 4;
    const int h    = bh & 15;
    const int q0   = blockIdx.y * 64 + wave * 16;

    const __bf16* Qp = Q  + (size_t)bh * SEQ * 64;
    const __bf16* Kp = Kb + (size_t)bh * SEQ * 64;
    const __bf16* Vp = Vb + (size_t)bh * SEQ * 64;
    const float*  Mp = mask + (size_t)b * SEQ * SEQ;

    // Q fragments (A-operand layout), held for the whole loop
    bf16x8 qf[2];
#pragma unroll
    for (int ks = 0; ks < 2; ++ks)
        qf[ks] = *(const bf16x8*)(Qp + (size_t)(q0 + l15) * 64 + ks * 32 + quad * 8);

    f32x4 oacc[4] = {};
    float mrun[4], lrun[4];
#pragma unroll
    for (int r = 0; r < 4; ++r) { mrun[r] = -1e30f; lrun[r] = 0.f; }

    for (int kt = 0; kt < SEQ / 64; ++kt) {
        const int key0 = kt * 64;
        __syncthreads();
        // stage V^T tile: Vt[d][key]
        {
            int idx = t * 8;
#pragma unroll
            for (int it = 0; it < 2; ++it) {
                int kr = idx >> 6;
                int d  = idx & 63;
                uint4 v = *(const uint4*)(Vp + (size_t)(key0 + kr) * 64 + d);
                __bf16 tmp[8];
                *(uint4*)tmp = v;
#pragma unroll
                for (int j = 0; j < 8; ++j) Vt[d + j][kr] = tmp[j];
                idx += 2048;
            }
        }
        // S = Q K^T  (B fragments direct from global; contiguous in dh)
        f32x4 sa[4];
#pragma unroll
        for (int nb = 0; nb < 4; ++nb) {
            f32x4 z = {};
            bf16x8 kf0 = *(const bf16x8*)(Kp + (size_t)(key0 + nb * 16 + l15) * 64 + quad * 8);
            bf16x8 kf1 = *(const bf16x8*)(Kp + (size_t)(key0 + nb * 16 + l15) * 64 + 32 + quad * 8);
            z = __builtin_amdgcn_mfma_f32_16x16x32_bf16(qf[0], kf0, z, 0, 0, 0);
            z = __builtin_amdgcn_mfma_f32_16x16x32_bf16(qf[1], kf1, z, 0, 0, 0);
            sa[nb] = z;
        }
        // mask + scale (fp32)
        float s[4][4];
#pragma unroll
        for (int nb = 0; nb < 4; ++nb) {
            int key = key0 + nb * 16 + l15;
#pragma unroll
            for (int r = 0; r < 4; ++r) {
                int qq = q0 + quad * 4 + r;
                float m = Mp[(size_t)qq * SEQ + key];
                s[nb][r] = sa[nb][r] * 0.125f * m + (m - 1.0f) * 10000.0f;
            }
        }
        // online softmax: row = (quad,reg); reduce across 16 lanes (cols)
        float alpha[4];
#pragma unroll
        for (int r = 0; r < 4; ++r) {
            float v = fmaxf(fmaxf(s[0][r], s[1][r]), fmaxf(s[2][r], s[3][r]));
            v = fmaxf(v, __shfl_xor(v, 1));
            v = fmaxf(v, __shfl_xor(v, 2));
            v = fmaxf(v, __shfl_xor(v, 4));
            v = fmaxf(v, __shfl_xor(v, 8));
            float mnew = fmaxf(mrun[r], v);
            alpha[r] = __expf(mrun[r] - mnew);
            mrun[r] = mnew;
        }
#pragma unroll
        for (int r = 0; r < 4; ++r) {
            float accs = 0.f;
#pragma unroll
            for (int nb = 0; nb < 4; ++nb) {
                float p = __expf(s[nb][r] - mrun[r]);
                s[nb][r] = p;
                accs += p;
            }
            accs += __shfl_xor(accs, 1);
            accs += __shfl_xor(accs, 2);
            accs += __shfl_xor(accs, 4);
            accs += __shfl_xor(accs, 8);
            lrun[r] = lrun[r] * alpha[r] + accs;
        }
        // P: C-layout -> LDS -> A-layout
#pragma unroll
        for (int nb = 0; nb < 4; ++nb)
#pragma unroll
            for (int r = 0; r < 4; ++r)
                Ps[wave][quad * 4 + r][nb * 16 + l15] = (__bf16)s[nb][r];
        __syncthreads();
        // rescale O, then O += P V
#pragma unroll
        for (int cb = 0; cb < 4; ++cb)
#pragma unroll
            for (int r = 0; r < 4; ++r)
                oacc[cb][r] *= alpha[r];
        bf16x8 pf[2];
#pragma unroll
        for (int ks = 0; ks < 2; ++ks)
            pf[ks] = *(const bf16x8*)(&Ps[wave][l15][ks * 32 + quad * 8]);
#pragma unroll
        for (int cb = 0; cb < 4; ++cb) {
#pragma unroll
            for (int ks = 0; ks < 2; ++ks) {
                bf16x8 vf = *(const bf16x8*)(&Vt[cb * 16 + l15][ks * 32 + quad * 8]);
                oacc[cb] = __builtin_amdgcn_mfma_f32_16x16x32_bf16(pf[ks], vf, oacc[cb], 0, 0, 0);
            }
        }
    }
    // epilogue: Out[b][q][h*64 + d] (bf16 — feeds GEMM2's bf16 A path)
#pragma unroll
    for (int cb = 0; cb < 4; ++cb) {
#pragma unroll
        for (int r = 0; r < 4; ++r) {
            int qq = q0 + quad * 4 + r;
            float v = oacc[cb][r] / lrun[r];
            Out[((size_t)(b * SEQ + qq)) * DMODEL + h * 64 + cb * 16 + l15] = (__bf16)v;
        }
    }
}

// ---------------------------------------------------------------------------
extern "C" void kernel_launch(void* const* d_in, const int* in_sizes, int n_in,
                              void* d_out, int out_size, void* d_ws, size_t ws_size,
                              hipStream_t stream)
{
    // Size-keyed remap (all six sizes distinct); identity under documented order.
    const float* src  = nullptr;  // 4194304
    const float* mask = nullptr;  // 8388608
    const float* Wqkv = nullptr;  // 3145728
    const float* bqkv = nullptr;  // 3072
    const float* Wout = nullptr;  // 1048576
    const float* bout = nullptr;  // 1024
    for (int i = 0; i < n_in; ++i) {
        switch (in_sizes[i]) {
            case 4194304: src  = (const float*)d_in[i]; break;
            case 8388608: mask = (const float*)d_in[i]; break;
            case 3145728: Wqkv = (const float*)d_in[i]; break;
            case 3072:    bqkv = (const float*)d_in[i]; break;
            case 1048576: Wout = (const float*)d_in[i]; break;
            case 1024:    bout = (const float*)d_in[i]; break;
        }
    }
    float* out = (float*)d_out;                  // [2,2048,1024] FP32

    const size_t NE = (size_t)2 * 16 * SEQ * 64; // 4M elems per tensor
    __bf16* Qb = (__bf16*)d_ws;
    __bf16* Kb = Qb + NE;
    __bf16* Vb = Kb + NE;
    __bf16* Ao = Vb + NE;                        // attn out [B*S, 1024] bf16

    gemm_kernel<true><<<dim3(3072 / 128, 4096 / 128), 256, 0, stream>>>(
        (const void*)src, Wqkv, bqkv, Qb, Kb, Vb, nullptr, 1024, 3072, 0);

    attn_kernel<<<dim3(32, SEQ / 64), 256, 0, stream>>>(Qb, Kb, Vb, mask, Ao);

    gemm_kernel<false><<<dim3(1024 / 128, 4096 / 128), 256, 0, stream>>>(
        (const void*)Ao, Wout, bout, nullptr, nullptr, nullptr, out, 1024, 1024, 1);
}

// Round 6
// 339.493 us; speedup vs baseline: 5.3446x; 1.3299x over previous
//
#include <hip/hip_runtime.h>
#include <stdint.h>

// Problem: B=2, S=2048, D=1024, H=16, dh=64
// Inputs fp32, OUTPUT fp32. Internals bf16 (threshold has bf16 floor).
#define SEQ    2048
#define DMODEL 1024

typedef __bf16 bf16x8 __attribute__((ext_vector_type(8)));
typedef float  f32x4  __attribute__((ext_vector_type(4)));

typedef __attribute__((address_space(1))) const void CGV;  // global
typedef __attribute__((address_space(3))) void LDSV;       // LDS

__device__ __forceinline__ void load_lds16(const void* g, void* l) {
    __builtin_amdgcn_global_load_lds((CGV*)g, (LDSV*)l, 16, 0, 0);
}

// ---------------------------------------------------------------------------
// Transpose+convert: in f32 [R][C] -> out bf16 [C][R].  grid (C/32, R/32), 256 thr
// ---------------------------------------------------------------------------
__global__ __launch_bounds__(256)
void transpose_f32_to_bf16(const float* __restrict__ in, __bf16* __restrict__ out,
                           int R, int C)
{
    __shared__ float tile[32][33];
    const int t  = threadIdx.x;
    const int tx = t & 31, ty = t >> 5;          // ty 0..7
    const int c0 = blockIdx.x * 32;
    const int r0 = blockIdx.y * 32;
#pragma unroll
    for (int i = 0; i < 4; ++i)
        tile[ty + i * 8][tx] = in[(size_t)(r0 + ty + i * 8) * C + c0 + tx];
    __syncthreads();
#pragma unroll
    for (int i = 0; i < 4; ++i)
        out[(size_t)(c0 + ty + i * 8) * R + r0 + tx] = (__bf16)tile[tx][ty + i * 8];
}

// ---------------------------------------------------------------------------
// V transpose (bf16): in [32][2048][64] -> out [32][64][2048]
// grid (SEQ/32, 64/32, 32), 256 thr
// ---------------------------------------------------------------------------
__global__ __launch_bounds__(256)
void transpose_v(const __bf16* __restrict__ in, __bf16* __restrict__ out)
{
    __shared__ __bf16 tile[32][34];
    const int t  = threadIdx.x;
    const int tx = t & 31, ty = t >> 5;
    const int s0 = blockIdx.x * 32;
    const int d0 = blockIdx.y * 32;
    const int bh = blockIdx.z;
    const __bf16* ip = in  + (size_t)bh * SEQ * 64;
    __bf16*       op = out + (size_t)bh * 64 * SEQ;
#pragma unroll
    for (int i = 0; i < 4; ++i)
        tile[ty + i * 8][tx] = ip[(size_t)(s0 + ty + i * 8) * 64 + d0 + tx];
    __syncthreads();
#pragma unroll
    for (int i = 0; i < 4; ++i)
        op[(size_t)(d0 + ty + i * 8) * SEQ + s0 + tx] = tile[tx][ty + i * 8];
}

// ---------------------------------------------------------------------------
// GEMM (m97 structure): C[M x N] = A[M x K] @ Bt[N x K]^T + bias[N]
//   Bt: bf16, pre-transposed weights. A: fp32 (convert path) or bf16
//   (global_load_lds path). Unpadded LDS tiles (wave-uniform-base constraint).
// mode 0: scatter bf16 into Q/K/V [B,H,S,dh];  mode 1: fp32 row-major store.
// ---------------------------------------------------------------------------
template<bool A_IS_F32>
__global__ __launch_bounds__(256)
void gemm_kernel(const void* __restrict__ Av, const __bf16* __restrict__ Bt,
                 const float* __restrict__ bias,
                 __bf16* __restrict__ Cq, __bf16* __restrict__ Ck,
                 __bf16* __restrict__ Cv, float* __restrict__ Cplain,
                 int K, int N, int mode)
{
    __shared__ __attribute__((aligned(16))) __bf16 As[128][32];
    __shared__ __attribute__((aligned(16))) __bf16 Bs[128][32];

    const int t    = threadIdx.x;
    const int wave = __builtin_amdgcn_readfirstlane(t >> 6);
    const int lane = t & 63;
    const int l15  = lane & 15;
    const int quad = lane >> 4;
    const int wm   = (wave >> 1) * 64;
    const int wn   = (wave & 1) * 64;
    const int m0   = blockIdx.y * 128;
    const int n0   = blockIdx.x * 128;

    const int arow  = lane >> 2;        // 0..15 within a 16-row slab
    const int akoff = (lane & 3) * 8;   // lane covers 8 bf16 of k

    f32x4 acc[4][4] = {};

    for (int k0 = 0; k0 < K; k0 += 32) {
        __syncthreads();
        // ---- stage A 128x32 ----
        if (A_IS_F32) {
            const float* A = (const float*)Av;
            int row = t >> 1, kk = (t & 1) * 16;
            const float* srcp = A + (size_t)(m0 + row) * K + k0 + kk;
            float4 v0 = *(const float4*)(srcp);
            float4 v1 = *(const float4*)(srcp + 4);
            float4 v2 = *(const float4*)(srcp + 8);
            float4 v3 = *(const float4*)(srcp + 12);
            __bf16 tmp[16] = {
                (__bf16)v0.x, (__bf16)v0.y, (__bf16)v0.z, (__bf16)v0.w,
                (__bf16)v1.x, (__bf16)v1.y, (__bf16)v1.z, (__bf16)v1.w,
                (__bf16)v2.x, (__bf16)v2.y, (__bf16)v2.z, (__bf16)v2.w,
                (__bf16)v3.x, (__bf16)v3.y, (__bf16)v3.z, (__bf16)v3.w };
            *(uint4*)(&As[row][kk])     = *(uint4*)(tmp);
            *(uint4*)(&As[row][kk + 8]) = *(uint4*)(tmp + 8);
        } else {
            const __bf16* A = (const __bf16*)Av;
#pragma unroll
            for (int p = 0; p < 2; ++p) {
                int slab = (wave * 2 + p) * 16;
                const __bf16* g = A + (size_t)(m0 + slab + arow) * K + k0 + akoff;
                load_lds16(g, &As[slab][0]);   // HW: base + lane*16
            }
        }
        // ---- stage B 128x32 via global_load_lds (Bt is [N][K] bf16) ----
#pragma unroll
        for (int p = 0; p < 2; ++p) {
            int slab = (wave * 2 + p) * 16;
            const __bf16* g = Bt + (size_t)(n0 + slab + arow) * K + k0 + akoff;
            load_lds16(g, &Bs[slab][0]);
        }
        __syncthreads();   // drains vmcnt (global_load_lds) + lgkm

        bf16x8 af[4], bfr[4];
#pragma unroll
        for (int mi = 0; mi < 4; ++mi)
            af[mi] = *(const bf16x8*)(&As[wm + mi * 16 + l15][quad * 8]);
#pragma unroll
        for (int ni = 0; ni < 4; ++ni)
            bfr[ni] = *(const bf16x8*)(&Bs[wn + ni * 16 + l15][quad * 8]);
#pragma unroll
        for (int mi = 0; mi < 4; ++mi)
#pragma unroll
            for (int ni = 0; ni < 4; ++ni)
                acc[mi][ni] = __builtin_amdgcn_mfma_f32_16x16x32_bf16(
                    af[mi], bfr[ni], acc[mi][ni], 0, 0, 0);
    }

    // epilogue: C/D layout col=lane&15, row=quad*4+reg
#pragma unroll
    for (int mi = 0; mi < 4; ++mi) {
        int rowb = m0 + wm + mi * 16 + quad * 4;
#pragma unroll
        for (int ni = 0; ni < 4; ++ni) {
            int col = n0 + wn + ni * 16 + l15;
            float bia = bias[col];
#pragma unroll
            for (int r = 0; r < 4; ++r) {
                float v = acc[mi][ni][r] + bia;
                int rr = rowb + r;
                if (mode == 0) {
                    int b = rr >> 11;
                    int s = rr & 2047;
                    int part = col >> 10;
                    int rem  = col & 1023;
                    int h = rem >> 6;
                    int d = rem & 63;
                    __bf16* dst = (part == 0) ? Cq : (part == 1) ? Ck : Cv;
                    dst[(((size_t)(b * 16 + h)) * SEQ + s) * 64 + d] = (__bf16)v;
                } else {
                    Cplain[(size_t)rr * N + col] = v;   // fp32 output
                }
            }
        }
    }
}

// ---------------------------------------------------------------------------
// MFMA flash attention. V is PRE-TRANSPOSED in global: Vt_g [bh][d][s].
// grid (B*H=32, S/64=32); 4 waves, each wave owns 16 q rows.
// ---------------------------------------------------------------------------
__global__ __launch_bounds__(256)
void attn_kernel(const __bf16* __restrict__ Q, const __bf16* __restrict__ Kb,
                 const __bf16* __restrict__ Vtg, const float* __restrict__ mask,
                 __bf16* __restrict__ Out)
{
    __shared__ __attribute__((aligned(16))) __bf16 Vt[64][72];     // [d][key]
    __shared__ __attribute__((aligned(16))) __bf16 Ps[4][16][72];  // per-wave P

    const int t    = threadIdx.x;
    const int wave = t >> 6;
    const int lane = t & 63;
    const int l15  = lane & 15;
    const int quad = lane >> 4;
    const int bh   = blockIdx.x;
    const int b    = bh >> 4;
    const int h    = bh & 15;
    const int q0   = blockIdx.y * 64 + wave * 16;

    const __bf16* Qp  = Q   + (size_t)bh * SEQ * 64;
    const __bf16* Kp  = Kb  + (size_t)bh * SEQ * 64;
    const __bf16* Vtp = Vtg + (size_t)bh * 64 * SEQ;   // [d][s]
    const float*  Mp  = mask + (size_t)b * SEQ * SEQ;

    bf16x8 qf[2];
#pragma unroll
    for (int ks = 0; ks < 2; ++ks)
        qf[ks] = *(const bf16x8*)(Qp + (size_t)(q0 + l15) * 64 + ks * 32 + quad * 8);

    f32x4 oacc[4] = {};
    float mrun[4], lrun[4];
#pragma unroll
    for (int r = 0; r < 4; ++r) { mrun[r] = -1e30f; lrun[r] = 0.f; }

    for (int kt = 0; kt < SEQ / 64; ++kt) {
        const int key0 = kt * 64;
        __syncthreads();
        // stage V^T tile: coalesced rows from pre-transposed global
        {
            int idx = t * 8;
#pragma unroll
            for (int it2 = 0; it2 < 2; ++it2) {
                int d  = idx >> 6;
                int ky = idx & 63;
                *(uint4*)(&Vt[d][ky]) =
                    *(const uint4*)(Vtp + (size_t)d * SEQ + key0 + ky);
                idx += 2048;
            }
        }
        // S = Q K^T
        f32x4 sa[4];
#pragma unroll
        for (int nb = 0; nb < 4; ++nb) {
            f32x4 z = {};
            bf16x8 kf0 = *(const bf16x8*)(Kp + (size_t)(key0 + nb * 16 + l15) * 64 + quad * 8);
            bf16x8 kf1 = *(const bf16x8*)(Kp + (size_t)(key0 + nb * 16 + l15) * 64 + 32 + quad * 8);
            z = __builtin_amdgcn_mfma_f32_16x16x32_bf16(qf[0], kf0, z, 0, 0, 0);
            z = __builtin_amdgcn_mfma_f32_16x16x32_bf16(qf[1], kf1, z, 0, 0, 0);
            sa[nb] = z;
        }
        // mask + scale
        float s[4][4];
#pragma unroll
        for (int nb = 0; nb < 4; ++nb) {
            int key = key0 + nb * 16 + l15;
#pragma unroll
            for (int r = 0; r < 4; ++r) {
                int qq = q0 + quad * 4 + r;
                float m = Mp[(size_t)qq * SEQ + key];
                s[nb][r] = sa[nb][r] * 0.125f * m + (m - 1.0f) * 10000.0f;
            }
        }
        // online softmax
        float alpha[4];
#pragma unroll
        for (int r = 0; r < 4; ++r) {
            float v = fmaxf(fmaxf(s[0][r], s[1][r]), fmaxf(s[2][r], s[3][r]));
            v = fmaxf(v, __shfl_xor(v, 1));
            v = fmaxf(v, __shfl_xor(v, 2));
            v = fmaxf(v, __shfl_xor(v, 4));
            v = fmaxf(v, __shfl_xor(v, 8));
            float mnew = fmaxf(mrun[r], v);
            alpha[r] = __expf(mrun[r] - mnew);
            mrun[r] = mnew;
        }
#pragma unroll
        for (int r = 0; r < 4; ++r) {
            float accs = 0.f;
#pragma unroll
            for (int nb = 0; nb < 4; ++nb) {
                float p = __expf(s[nb][r] - mrun[r]);
                s[nb][r] = p;
                accs += p;
            }
            accs += __shfl_xor(accs, 1);
            accs += __shfl_xor(accs, 2);
            accs += __shfl_xor(accs, 4);
            accs += __shfl_xor(accs, 8);
            lrun[r] = lrun[r] * alpha[r] + accs;
        }
        // P: C-layout -> LDS -> A-layout
#pragma unroll
        for (int nb = 0; nb < 4; ++nb)
#pragma unroll
            for (int r = 0; r < 4; ++r)
                Ps[wave][quad * 4 + r][nb * 16 + l15] = (__bf16)s[nb][r];
        __syncthreads();
        // O = O*alpha + P V
#pragma unroll
        for (int cb = 0; cb < 4; ++cb)
#pragma unroll
            for (int r = 0; r < 4; ++r)
                oacc[cb][r] *= alpha[r];
        bf16x8 pf[2];
#pragma unroll
        for (int ks = 0; ks < 2; ++ks)
            pf[ks] = *(const bf16x8*)(&Ps[wave][l15][ks * 32 + quad * 8]);
#pragma unroll
        for (int cb = 0; cb < 4; ++cb) {
#pragma unroll
            for (int ks = 0; ks < 2; ++ks) {
                bf16x8 vf = *(const bf16x8*)(&Vt[cb * 16 + l15][ks * 32 + quad * 8]);
                oacc[cb] = __builtin_amdgcn_mfma_f32_16x16x32_bf16(pf[ks], vf, oacc[cb], 0, 0, 0);
            }
        }
    }
    // epilogue (bf16 Ao, feeds GEMM2's global_load_lds A path)
#pragma unroll
    for (int cb = 0; cb < 4; ++cb) {
#pragma unroll
        for (int r = 0; r < 4; ++r) {
            int qq = q0 + quad * 4 + r;
            float v = oacc[cb][r] / lrun[r];
            Out[((size_t)(b * SEQ + qq)) * DMODEL + h * 64 + cb * 16 + l15] = (__bf16)v;
        }
    }
}

// ---------------------------------------------------------------------------
extern "C" void kernel_launch(void* const* d_in, const int* in_sizes, int n_in,
                              void* d_out, int out_size, void* d_ws, size_t ws_size,
                              hipStream_t stream)
{
    const float* src  = nullptr;  // 4194304
    const float* mask = nullptr;  // 8388608
    const float* Wqkv = nullptr;  // 3145728
    const float* bqkv = nullptr;  // 3072
    const float* Wout = nullptr;  // 1048576
    const float* bout = nullptr;  // 1024
    for (int i = 0; i < n_in; ++i) {
        switch (in_sizes[i]) {
            case 4194304: src  = (const float*)d_in[i]; break;
            case 8388608: mask = (const float*)d_in[i]; break;
            case 3145728: Wqkv = (const float*)d_in[i]; break;
            case 3072:    bqkv = (const float*)d_in[i]; break;
            case 1048576: Wout = (const float*)d_in[i]; break;
            case 1024:    bout = (const float*)d_in[i]; break;
        }
    }
    float* out = (float*)d_out;                  // [2,2048,1024] fp32

    const size_t NE = (size_t)2 * 16 * SEQ * 64; // 4M elems
    __bf16* Qb     = (__bf16*)d_ws;              // 4M
    __bf16* Kb     = Qb + NE;                    // 4M
    __bf16* Vb     = Kb + NE;                    // 4M (dead after transpose_v)
    __bf16* Vtg    = Vb + NE;                    // 4M
    __bf16* Wqkv_t = Vtg + NE;                   // 3M  [3072][1024]
    __bf16* Wout_t = Wqkv_t + (size_t)3072 * 1024; // 1M [1024][1024]
    __bf16* Ao     = Vb;                         // alias: Vb dead by then
    // total: 4+4+4+4+3+1 = 20M bf16 = 40MB

    // weight transposes (bf16 convert)
    transpose_f32_to_bf16<<<dim3(3072 / 32, 1024 / 32), 256, 0, stream>>>(
        Wqkv, Wqkv_t, 1024, 3072);
    transpose_f32_to_bf16<<<dim3(1024 / 32, 1024 / 32), 256, 0, stream>>>(
        Wout, Wout_t, 1024, 1024);

    // GEMM1: src(f32) @ Wqkv -> scatter Q/K/V
    gemm_kernel<true><<<dim3(3072 / 128, 4096 / 128), 256, 0, stream>>>(
        (const void*)src, Wqkv_t, bqkv, Qb, Kb, Vb, nullptr, 1024, 3072, 0);

    // V -> V^T
    transpose_v<<<dim3(SEQ / 32, 2, 32), 256, 0, stream>>>(Vb, Vtg);

    // attention
    attn_kernel<<<dim3(32, SEQ / 64), 256, 0, stream>>>(Qb, Kb, Vtg, mask, Ao);

    // GEMM2: Ao(bf16) @ Wout + b -> out (fp32)
    gemm_kernel<false><<<dim3(1024 / 128, 4096 / 128), 256, 0, stream>>>(
        (const void*)Ao, Wout_t, bout, nullptr, nullptr, nullptr, out, 1024, 1024, 1);
}